// Round 3
// baseline (323.295 us; speedup 1.0000x reference)
//
#include <hip/hip_runtime.h>
#include <stdint.h>

// ============================================================================
// LaneGraphConvLayerShared: NNConv(edge-conditioned) + root + residual + LN
//
// msg[e,f] = sum_{k<16} a[e,k]*(x[src]@W_k)[f] + (x[src]@B_bias)[f]
//          = (A_e @ W2)[f], A_e[k*64+d] = a[e,k]*x[src,d]; slot 16: a=1, rows=b_edge
//
// R1: edge_kernel was latency-bound (MfmaUtil 12%, VGPR 56 -> no prefetch of
// the 136 B-frag L2 loads per tile). New structure: B fragments live in
// REGISTERS, slot-split across the 4 waves (wave w: slots {w,w+4,w+8,w+12},
// waves 2/3 additionally one K-half each of bias slot 16). Loaded once per
// block; block grid-strides over ~4.6 edge tiles. Partials reduced via LDS,
// atomics scatter. x/a/dst staging loads issued early (hidden under MFMA).
// R2: resubmit of R1 (container died mid-bench; no signal).
// ============================================================================

#define NSLOT 17

typedef short short8 __attribute__((ext_vector_type(8)));
typedef float floatx4 __attribute__((ext_vector_type(4)));

union AFrag { short8 s8; uint32_t u[4]; };

__device__ __forceinline__ uint32_t cvt_pk_bf16(float lo, float hi) {
  uint32_t r;
  asm("v_cvt_pk_bf16_f32 %0, %1, %2" : "=v"(r) : "v"(lo), "v"(hi));
  return r;
}

__device__ __forceinline__ uint16_t f32_to_bf16_bits(float x) {
  uint32_t u = __float_as_uint(x);
  u += 0x7fffu + ((u >> 16) & 1u);
  return (uint16_t)(u >> 16);
}

// ws layout:
//   [0,        139264): W2frag  bf16 [slot17][kstep2][c4][lane64][i8]
//   [139264,   147456): Wsumfrag bf16 [kstep2][c4][lane64][i8]  (W_root+W_res)
//   [147456,   147712): bsum f32 [64]  (bias + b_res)
#define W2FRAG_OFF 0
#define WSUM_OFF   139264
#define BSUM_OFF   147456
#define PREP_TOTAL 73792   // 69632 + 4096 + 64

__global__ __launch_bounds__(256) void prep_kernel(
    const float* __restrict__ W_edge, const float* __restrict__ b_edge,
    const float* __restrict__ W_root, const float* __restrict__ bias,
    const float* __restrict__ W_res,  const float* __restrict__ b_res,
    uint16_t* __restrict__ w2frag, uint16_t* __restrict__ wsumfrag,
    float* __restrict__ bsum) {
  int gid = blockIdx.x * 256 + threadIdx.x;
  if (gid < 69632) {
    int i = gid & 7, l = (gid >> 3) & 63, c = (gid >> 9) & 3;
    int t = (gid >> 11) & 1, s = gid >> 12;
    int d = t * 32 + 8 * (l >> 4) + i;
    int f = c * 16 + (l & 15);
    float v = (s < 16) ? W_edge[s * 4096 + d * 64 + f] : b_edge[d * 64 + f];
    w2frag[gid] = f32_to_bf16_bits(v);
  } else if (gid < 73728) {
    int g = gid - 69632;
    int i = g & 7, l = (g >> 3) & 63, c = (g >> 9) & 3, t = (g >> 11) & 1;
    int d = t * 32 + 8 * (l >> 4) + i;
    int f = c * 16 + (l & 15);
    wsumfrag[g] = f32_to_bf16_bits(W_root[d * 64 + f] + W_res[d * 64 + f]);
  } else if (gid < PREP_TOTAL) {
    int f = gid - 73728;
    bsum[f] = bias[f] + b_res[f];
  }
}

// base: out[n,f] = sum_d x[n,d]*(W_root+W_res)[d,f] + bias[f]+b_res[f]
__global__ __launch_bounds__(256) void base_kernel(
    const float* __restrict__ x, const uint16_t* __restrict__ wsumfrag,
    const float* __restrict__ bsum, float* __restrict__ out, int N) {
  int w = threadIdx.x >> 6, l = threadIdx.x & 63;
  int l16 = l & 15, lq = l >> 4;
  int arow = blockIdx.x * 64 + w * 16 + l16;
  float xv[16];
#pragma unroll
  for (int t = 0; t < 2; ++t)
#pragma unroll
    for (int i = 0; i < 8; ++i)
      xv[t * 8 + i] = (arow < N) ? x[arow * 64 + t * 32 + 8 * lq + i] : 0.0f;
  AFrag A[2];
#pragma unroll
  for (int t = 0; t < 2; ++t)
#pragma unroll
    for (int j = 0; j < 4; ++j)
      A[t].u[j] = cvt_pk_bf16(xv[t * 8 + 2 * j], xv[t * 8 + 2 * j + 1]);
  floatx4 acc[4];
#pragma unroll
  for (int c = 0; c < 4; ++c) acc[c] = (floatx4){0.f, 0.f, 0.f, 0.f};
  const short8* bp = (const short8*)wsumfrag;
#pragma unroll
  for (int t = 0; t < 2; ++t)
#pragma unroll
    for (int c = 0; c < 4; ++c) {
      short8 B = bp[(t * 4 + c) * 64 + l];
      acc[c] = __builtin_amdgcn_mfma_f32_16x16x32_bf16(A[t].s8, B, acc[c], 0, 0, 0);
    }
#pragma unroll
  for (int c = 0; c < 4; ++c) {
    int f = c * 16 + l16;
    float bs = bsum[f];
#pragma unroll
    for (int r = 0; r < 4; ++r) {
      int row = blockIdx.x * 64 + w * 16 + lq * 4 + r;
      if (row < N) out[row * 64 + f] = acc[c][r] + bs;
    }
  }
}

// edge: grid-stride over 64-edge tiles. B-frags register-resident, slot-split
// across waves; LDS cross-wave reduction; atomic scatter to out[dst].
__global__ __launch_bounds__(256, 2) void edge_kernel(
    const float* __restrict__ x, const int* __restrict__ eidx,
    const float* __restrict__ attr, const uint16_t* __restrict__ w2frag,
    float* __restrict__ out, int E) {
  __shared__ float x_lds[64][68];
  __shared__ float a_lds[64][17];
  __shared__ int   dst_lds[64];
  __shared__ float red[4][32][68];

  int tid = threadIdx.x;
  int w = tid >> 6, l = tid & 63, l16 = l & 15, lq = l >> 4;
  int row = tid >> 2, q = tid & 3;
  const int* srcp = eidx;
  const int* dstp = eidx + E;
  const float4* x4 = (const float4*)x;
  const float4* a4 = (const float4*)attr;
  int T = (E + 63) >> 6;
  const short8* bp = (const short8*)w2frag;

  // ---- B fragments -> registers (once per block) ----
  short8 Breg[4][2][4];
#pragma unroll
  for (int si = 0; si < 4; ++si) {
    int s = 4 * si + w;
#pragma unroll
    for (int t = 0; t < 2; ++t)
#pragma unroll
      for (int c = 0; c < 4; ++c)
        Breg[si][t][c] = bp[((s * 2 + t) * 4 + c) * 64 + l];
  }
  int tx = w - 2;  // waves 2,3 take K-halves of bias slot 16
  short8 Bx[4];
  if (tx >= 0) {
#pragma unroll
    for (int c = 0; c < 4; ++c) Bx[c] = bp[((32 + tx) * 4 + c) * 64 + l];
  }

  // ---- stage first tile ----
  int tl = blockIdx.x;
  if (tl < T) {
    int cnt0 = min(64, E - tl * 64);
    bool ok = row < cnt0;
    int sidx = ok ? srcp[tl * 64 + row] : 0;
#pragma unroll
    for (int j = 0; j < 4; ++j) {
      float4 v = make_float4(0.f, 0.f, 0.f, 0.f);
      if (ok) v = x4[sidx * 16 + q * 4 + j];
      *(float4*)&x_lds[row][q * 16 + j * 4] = v;
    }
    float4 av = make_float4(0.f, 0.f, 0.f, 0.f);
    if (ok) av = a4[(tl * 64 + row) * 4 + q];
    a_lds[row][q * 4 + 0] = av.x;
    a_lds[row][q * 4 + 1] = av.y;
    a_lds[row][q * 4 + 2] = av.z;
    a_lds[row][q * 4 + 3] = av.w;
    if (q == 0) dst_lds[row] = ok ? dstp[tl * 64 + row] : 0;
  }
  __syncthreads();

  for (; tl < T; tl += gridDim.x) {
    int cnt = min(64, E - tl * 64);
    int nxt = tl + (int)gridDim.x;
    bool havenxt = nxt < T;
    // early-issue next tile's gather (T14): consumed only at stage-write below
    float4 xr[4];
    float4 ar = make_float4(0.f, 0.f, 0.f, 0.f);
    int dv = 0;
    if (havenxt) {
      int cntn = min(64, E - nxt * 64);
      bool ok = row < cntn;
      int sidx = ok ? srcp[nxt * 64 + row] : 0;
#pragma unroll
      for (int j = 0; j < 4; ++j) {
        xr[j] = make_float4(0.f, 0.f, 0.f, 0.f);
        if (ok) xr[j] = x4[sidx * 16 + q * 4 + j];
      }
      if (ok) ar = a4[(nxt * 64 + row) * 4 + q];
      if (ok) dv = dstp[nxt * 64 + row];
    }

#pragma unroll
    for (int p = 0; p < 2; ++p) {
      floatx4 acc[2][4];
#pragma unroll
      for (int rt = 0; rt < 2; ++rt)
#pragma unroll
        for (int c = 0; c < 4; ++c) acc[rt][c] = (floatx4){0.f, 0.f, 0.f, 0.f};

#pragma unroll
      for (int rt = 0; rt < 2; ++rt) {
        int arow = p * 32 + rt * 16 + l16;
        float xv[16];
#pragma unroll
        for (int t2 = 0; t2 < 2; ++t2)
#pragma unroll
          for (int i = 0; i < 8; ++i)
            xv[t2 * 8 + i] = x_lds[arow][t2 * 32 + 8 * lq + i];
#pragma unroll
        for (int si = 0; si < 4; ++si) {
          float av = a_lds[arow][4 * si + w];
#pragma unroll
          for (int t = 0; t < 2; ++t) {
            AFrag A;
#pragma unroll
            for (int j = 0; j < 4; ++j)
              A.u[j] = cvt_pk_bf16(av * xv[t * 8 + 2 * j], av * xv[t * 8 + 2 * j + 1]);
#pragma unroll
            for (int c = 0; c < 4; ++c)
              acc[rt][c] = __builtin_amdgcn_mfma_f32_16x16x32_bf16(
                  A.s8, Breg[si][t][c], acc[rt][c], 0, 0, 0);
          }
        }
        if (tx >= 0) {  // bias slot, a == 1, K-half tx
          AFrag A;
#pragma unroll
          for (int j = 0; j < 4; ++j)
            A.u[j] = cvt_pk_bf16(xv[tx * 8 + 2 * j], xv[tx * 8 + 2 * j + 1]);
#pragma unroll
          for (int c = 0; c < 4; ++c)
            acc[rt][c] = __builtin_amdgcn_mfma_f32_16x16x32_bf16(
                A.s8, Bx[c], acc[rt][c], 0, 0, 0);
        }
      }

      // partial -> LDS
#pragma unroll
      for (int rt = 0; rt < 2; ++rt)
#pragma unroll
        for (int c = 0; c < 4; ++c) {
          int f = c * 16 + l16;
#pragma unroll
          for (int r = 0; r < 4; ++r)
            red[w][rt * 16 + lq * 4 + r][f] = acc[rt][c][r];
        }
      __syncthreads();

      // cross-wave reduce + atomic scatter: thread -> (edge er, 8-f chunk fq)
      {
        int er = tid >> 3, fq = tid & 7;
        floatx4 s0 = (floatx4){0.f, 0.f, 0.f, 0.f};
        floatx4 s1 = (floatx4){0.f, 0.f, 0.f, 0.f};
#pragma unroll
        for (int ww = 0; ww < 4; ++ww) {
          s0 += *(const floatx4*)&red[ww][er][fq * 8];
          s1 += *(const floatx4*)&red[ww][er][fq * 8 + 4];
        }
        int grow = p * 32 + er;
        if (grow < cnt) {
          float* op = out + dst_lds[grow] * 64 + fq * 8;
          atomicAdd(op + 0, s0[0]);
          atomicAdd(op + 1, s0[1]);
          atomicAdd(op + 2, s0[2]);
          atomicAdd(op + 3, s0[3]);
          atomicAdd(op + 4, s1[0]);
          atomicAdd(op + 5, s1[1]);
          atomicAdd(op + 6, s1[2]);
          atomicAdd(op + 7, s1[3]);
        }
      }
      __syncthreads();  // red reusable / x_lds reads all done after p=1
    }

    // stage next tile into the (single) buffer; safe: all reads completed
    if (havenxt) {
#pragma unroll
      for (int j = 0; j < 4; ++j) *(float4*)&x_lds[row][q * 16 + j * 4] = xr[j];
      a_lds[row][q * 4 + 0] = ar.x;
      a_lds[row][q * 4 + 1] = ar.y;
      a_lds[row][q * 4 + 2] = ar.z;
      a_lds[row][q * 4 + 3] = ar.w;
      if (q == 0) dst_lds[row] = dv;
    }
    __syncthreads();
  }
}

__global__ __launch_bounds__(256) void ln_kernel(
    float* __restrict__ out, const float* __restrict__ gamma,
    const float* __restrict__ beta, int N) {
  int w = threadIdx.x >> 6, l = threadIdx.x & 63;
  int row = blockIdx.x * 4 + w;
  if (row >= N) return;
  float v = out[row * 64 + l];
  float s = v;
#pragma unroll
  for (int m = 32; m >= 1; m >>= 1) s += __shfl_xor(s, m);
  float mu = s * 0.015625f;
  float d = v - mu;
  float q = d * d;
#pragma unroll
  for (int m = 32; m >= 1; m >>= 1) q += __shfl_xor(q, m);
  float var = q * 0.015625f;
  out[row * 64 + l] = d * rsqrtf(var + 1e-5f) * gamma[l] + beta[l];
}

extern "C" void kernel_launch(void* const* d_in, const int* in_sizes, int n_in,
                              void* d_out, int out_size, void* d_ws, size_t ws_size,
                              hipStream_t stream) {
  const float* x      = (const float*)d_in[0];
  const int*   eidx   = (const int*)d_in[1];
  const float* attr   = (const float*)d_in[2];
  const float* W_edge = (const float*)d_in[3];
  const float* b_edge = (const float*)d_in[4];
  const float* W_root = (const float*)d_in[5];
  const float* bias   = (const float*)d_in[6];
  const float* W_res  = (const float*)d_in[7];
  const float* b_res  = (const float*)d_in[8];
  const float* gamma  = (const float*)d_in[9];
  const float* beta   = (const float*)d_in[10];
  int N = in_sizes[0] / 64;
  int E = in_sizes[1] / 2;
  float* out = (float*)d_out;
  uint16_t* w2frag   = (uint16_t*)((char*)d_ws + W2FRAG_OFF);
  uint16_t* wsumfrag = (uint16_t*)((char*)d_ws + WSUM_OFF);
  float*    bsum     = (float*)((char*)d_ws + BSUM_OFF);

  prep_kernel<<<(PREP_TOTAL + 255) / 256, 256, 0, stream>>>(
      W_edge, b_edge, W_root, bias, W_res, b_res, w2frag, wsumfrag, bsum);
  base_kernel<<<(N + 63) / 64, 256, 0, stream>>>(x, wsumfrag, bsum, out, N);
  int T = (E + 63) / 64;
  int G = T < 512 ? T : 512;
  edge_kernel<<<G, 256, 0, stream>>>(x, eidx, attr, w2frag, out, E);
  ln_kernel<<<(N + 3) / 4, 256, 0, stream>>>(out, gamma, beta, N);
}

// Round 4
// 90.341 us; speedup vs baseline: 3.5786x; 3.5786x over previous
//
#include <hip/hip_runtime.h>
#include <stdint.h>

// ============================================================================
// LaneGraphConvLayerShared: NNConv(edge-conditioned) + root + residual + LN
//
// msg[e,f] = sum_{k<16} a[e,k]*(x[src]@W_k)[f] + (x[src]@B_bias)[f]
//          = (A_e @ W2)[f], A_e[k*64+d] = a[e,k]*x[src,d]; slot 16: a=1, rows=b_edge
//
// R1: B fragments register-resident, slot-split across 4 waves; grid-stride
//     tiles; LDS cross-wave reduction; early-issued gathers.
// R3 post-mortem: scatter with strided scalar atomics caused 32B/atomic HBM
//     writeback (WRITE_SIZE 300MB, pure write-bound, 294us). R4: restore the
//     R0 line-coalesced scatter: each atomic wave-instr = 4 rows x 16
//     consecutive floats -> TCC merges full lines (~4B/atomic, 37.5MB).
// ============================================================================

#define NSLOT 17

typedef short short8 __attribute__((ext_vector_type(8)));
typedef float floatx4 __attribute__((ext_vector_type(4)));

union AFrag { short8 s8; uint32_t u[4]; };

__device__ __forceinline__ uint32_t cvt_pk_bf16(float lo, float hi) {
  uint32_t r;
  asm("v_cvt_pk_bf16_f32 %0, %1, %2" : "=v"(r) : "v"(lo), "v"(hi));
  return r;
}

__device__ __forceinline__ uint16_t f32_to_bf16_bits(float x) {
  uint32_t u = __float_as_uint(x);
  u += 0x7fffu + ((u >> 16) & 1u);
  return (uint16_t)(u >> 16);
}

// ws layout:
//   [0,        139264): W2frag  bf16 [slot17][kstep2][c4][lane64][i8]
//   [139264,   147456): Wsumfrag bf16 [kstep2][c4][lane64][i8]  (W_root+W_res)
//   [147456,   147712): bsum f32 [64]  (bias + b_res)
#define W2FRAG_OFF 0
#define WSUM_OFF   139264
#define BSUM_OFF   147456
#define PREP_TOTAL 73792   // 69632 + 4096 + 64

__global__ __launch_bounds__(256) void prep_kernel(
    const float* __restrict__ W_edge, const float* __restrict__ b_edge,
    const float* __restrict__ W_root, const float* __restrict__ bias,
    const float* __restrict__ W_res,  const float* __restrict__ b_res,
    uint16_t* __restrict__ w2frag, uint16_t* __restrict__ wsumfrag,
    float* __restrict__ bsum) {
  int gid = blockIdx.x * 256 + threadIdx.x;
  if (gid < 69632) {
    int i = gid & 7, l = (gid >> 3) & 63, c = (gid >> 9) & 3;
    int t = (gid >> 11) & 1, s = gid >> 12;
    int d = t * 32 + 8 * (l >> 4) + i;
    int f = c * 16 + (l & 15);
    float v = (s < 16) ? W_edge[s * 4096 + d * 64 + f] : b_edge[d * 64 + f];
    w2frag[gid] = f32_to_bf16_bits(v);
  } else if (gid < 73728) {
    int g = gid - 69632;
    int i = g & 7, l = (g >> 3) & 63, c = (g >> 9) & 3, t = (g >> 11) & 1;
    int d = t * 32 + 8 * (l >> 4) + i;
    int f = c * 16 + (l & 15);
    wsumfrag[g] = f32_to_bf16_bits(W_root[d * 64 + f] + W_res[d * 64 + f]);
  } else if (gid < PREP_TOTAL) {
    int f = gid - 73728;
    bsum[f] = bias[f] + b_res[f];
  }
}

// base: out[n,f] = sum_d x[n,d]*(W_root+W_res)[d,f] + bias[f]+b_res[f]
__global__ __launch_bounds__(256) void base_kernel(
    const float* __restrict__ x, const uint16_t* __restrict__ wsumfrag,
    const float* __restrict__ bsum, float* __restrict__ out, int N) {
  int w = threadIdx.x >> 6, l = threadIdx.x & 63;
  int l16 = l & 15, lq = l >> 4;
  int arow = blockIdx.x * 64 + w * 16 + l16;
  float xv[16];
#pragma unroll
  for (int t = 0; t < 2; ++t)
#pragma unroll
    for (int i = 0; i < 8; ++i)
      xv[t * 8 + i] = (arow < N) ? x[arow * 64 + t * 32 + 8 * lq + i] : 0.0f;
  AFrag A[2];
#pragma unroll
  for (int t = 0; t < 2; ++t)
#pragma unroll
    for (int j = 0; j < 4; ++j)
      A[t].u[j] = cvt_pk_bf16(xv[t * 8 + 2 * j], xv[t * 8 + 2 * j + 1]);
  floatx4 acc[4];
#pragma unroll
  for (int c = 0; c < 4; ++c) acc[c] = (floatx4){0.f, 0.f, 0.f, 0.f};
  const short8* bp = (const short8*)wsumfrag;
#pragma unroll
  for (int t = 0; t < 2; ++t)
#pragma unroll
    for (int c = 0; c < 4; ++c) {
      short8 B = bp[(t * 4 + c) * 64 + l];
      acc[c] = __builtin_amdgcn_mfma_f32_16x16x32_bf16(A[t].s8, B, acc[c], 0, 0, 0);
    }
#pragma unroll
  for (int c = 0; c < 4; ++c) {
    int f = c * 16 + l16;
    float bs = bsum[f];
#pragma unroll
    for (int r = 0; r < 4; ++r) {
      int row = blockIdx.x * 64 + w * 16 + lq * 4 + r;
      if (row < N) out[row * 64 + f] = acc[c][r] + bs;
    }
  }
}

// edge: grid-stride over 64-edge tiles. B-frags register-resident, slot-split
// across waves; LDS cross-wave reduction; LINE-COALESCED atomic scatter.
__global__ __launch_bounds__(256, 2) void edge_kernel(
    const float* __restrict__ x, const int* __restrict__ eidx,
    const float* __restrict__ attr, const uint16_t* __restrict__ w2frag,
    float* __restrict__ out, int E) {
  __shared__ float x_lds[64][68];
  __shared__ float a_lds[64][17];
  __shared__ int   dst_lds[64];
  __shared__ float red[4][32][68];

  int tid = threadIdx.x;
  int w = tid >> 6, l = tid & 63, l16 = l & 15, lq = l >> 4;
  int row = tid >> 2, q = tid & 3;
  const int* srcp = eidx;
  const int* dstp = eidx + E;
  const float4* x4 = (const float4*)x;
  const float4* a4 = (const float4*)attr;
  int T = (E + 63) >> 6;
  const short8* bp = (const short8*)w2frag;

  // ---- B fragments -> registers (once per block) ----
  short8 Breg[4][2][4];
#pragma unroll
  for (int si = 0; si < 4; ++si) {
    int s = 4 * si + w;
#pragma unroll
    for (int t = 0; t < 2; ++t)
#pragma unroll
      for (int c = 0; c < 4; ++c)
        Breg[si][t][c] = bp[((s * 2 + t) * 4 + c) * 64 + l];
  }
  int tx = w - 2;  // waves 2,3 take K-halves of bias slot 16
  short8 Bx[4];
  if (tx >= 0) {
#pragma unroll
    for (int c = 0; c < 4; ++c) Bx[c] = bp[((32 + tx) * 4 + c) * 64 + l];
  }

  // ---- stage first tile ----
  int tl = blockIdx.x;
  if (tl < T) {
    int cnt0 = min(64, E - tl * 64);
    bool ok = row < cnt0;
    int sidx = ok ? srcp[tl * 64 + row] : 0;
#pragma unroll
    for (int j = 0; j < 4; ++j) {
      float4 v = make_float4(0.f, 0.f, 0.f, 0.f);
      if (ok) v = x4[sidx * 16 + q * 4 + j];
      *(float4*)&x_lds[row][q * 16 + j * 4] = v;
    }
    float4 av = make_float4(0.f, 0.f, 0.f, 0.f);
    if (ok) av = a4[(tl * 64 + row) * 4 + q];
    a_lds[row][q * 4 + 0] = av.x;
    a_lds[row][q * 4 + 1] = av.y;
    a_lds[row][q * 4 + 2] = av.z;
    a_lds[row][q * 4 + 3] = av.w;
    if (q == 0) dst_lds[row] = ok ? dstp[tl * 64 + row] : 0;
  }
  __syncthreads();

  for (; tl < T; tl += gridDim.x) {
    int cnt = min(64, E - tl * 64);
    int nxt = tl + (int)gridDim.x;
    bool havenxt = nxt < T;
    // early-issue next tile's gather (T14): consumed only at stage-write below
    float4 xr[4];
    float4 ar = make_float4(0.f, 0.f, 0.f, 0.f);
    int dv = 0;
    if (havenxt) {
      int cntn = min(64, E - nxt * 64);
      bool ok = row < cntn;
      int sidx = ok ? srcp[nxt * 64 + row] : 0;
#pragma unroll
      for (int j = 0; j < 4; ++j) {
        xr[j] = make_float4(0.f, 0.f, 0.f, 0.f);
        if (ok) xr[j] = x4[sidx * 16 + q * 4 + j];
      }
      if (ok) ar = a4[(nxt * 64 + row) * 4 + q];
      if (ok) dv = dstp[nxt * 64 + row];
    }

#pragma unroll
    for (int p = 0; p < 2; ++p) {
      floatx4 acc[2][4];
#pragma unroll
      for (int rt = 0; rt < 2; ++rt)
#pragma unroll
        for (int c = 0; c < 4; ++c) acc[rt][c] = (floatx4){0.f, 0.f, 0.f, 0.f};

#pragma unroll
      for (int rt = 0; rt < 2; ++rt) {
        int arow = p * 32 + rt * 16 + l16;
        float xv[16];
#pragma unroll
        for (int t2 = 0; t2 < 2; ++t2)
#pragma unroll
          for (int i = 0; i < 8; ++i)
            xv[t2 * 8 + i] = x_lds[arow][t2 * 32 + 8 * lq + i];
#pragma unroll
        for (int si = 0; si < 4; ++si) {
          float av = a_lds[arow][4 * si + w];
#pragma unroll
          for (int t = 0; t < 2; ++t) {
            AFrag A;
#pragma unroll
            for (int j = 0; j < 4; ++j)
              A.u[j] = cvt_pk_bf16(av * xv[t * 8 + 2 * j], av * xv[t * 8 + 2 * j + 1]);
#pragma unroll
            for (int c = 0; c < 4; ++c)
              acc[rt][c] = __builtin_amdgcn_mfma_f32_16x16x32_bf16(
                  A.s8, Breg[si][t][c], acc[rt][c], 0, 0, 0);
          }
        }
        if (tx >= 0) {  // bias slot, a == 1, K-half tx
          AFrag A;
#pragma unroll
          for (int j = 0; j < 4; ++j)
            A.u[j] = cvt_pk_bf16(xv[tx * 8 + 2 * j], xv[tx * 8 + 2 * j + 1]);
#pragma unroll
          for (int c = 0; c < 4; ++c)
            acc[rt][c] = __builtin_amdgcn_mfma_f32_16x16x32_bf16(
                A.s8, Bx[c], acc[rt][c], 0, 0, 0);
        }
      }

      // partial -> LDS
#pragma unroll
      for (int rt = 0; rt < 2; ++rt)
#pragma unroll
        for (int c = 0; c < 4; ++c) {
          int f = c * 16 + l16;
#pragma unroll
          for (int r = 0; r < 4; ++r)
            red[w][rt * 16 + lq * 4 + r][f] = acc[rt][c][r];
        }
      __syncthreads();

      // cross-wave reduce + LINE-COALESCED atomic scatter:
      // thread (w,l): rows w*8 + lq*2 + r (r<2), f = c*16 + l16.
      // Per atomic wave-instr: 4 rows x 16 CONSECUTIVE floats -> full-line
      // merge in TCC (~4B/atomic writeback).
#pragma unroll
      for (int c = 0; c < 4; ++c) {
        int f = c * 16 + l16;
#pragma unroll
        for (int r = 0; r < 2; ++r) {
          int rr = w * 8 + lq * 2 + r;
          float s = red[0][rr][f] + red[1][rr][f] + red[2][rr][f] + red[3][rr][f];
          int grow = p * 32 + rr;
          if (grow < cnt) atomicAdd(&out[dst_lds[grow] * 64 + f], s);
        }
      }
      __syncthreads();  // red reusable / x_lds reads all done after p=1
    }

    // stage next tile into the (single) buffer; safe: all reads completed
    if (havenxt) {
#pragma unroll
      for (int j = 0; j < 4; ++j) *(float4*)&x_lds[row][q * 16 + j * 4] = xr[j];
      a_lds[row][q * 4 + 0] = ar.x;
      a_lds[row][q * 4 + 1] = ar.y;
      a_lds[row][q * 4 + 2] = ar.z;
      a_lds[row][q * 4 + 3] = ar.w;
      if (q == 0) dst_lds[row] = dv;
    }
    __syncthreads();
  }
}

__global__ __launch_bounds__(256) void ln_kernel(
    float* __restrict__ out, const float* __restrict__ gamma,
    const float* __restrict__ beta, int N) {
  int w = threadIdx.x >> 6, l = threadIdx.x & 63;
  int row = blockIdx.x * 4 + w;
  if (row >= N) return;
  float v = out[row * 64 + l];
  float s = v;
#pragma unroll
  for (int m = 32; m >= 1; m >>= 1) s += __shfl_xor(s, m);
  float mu = s * 0.015625f;
  float d = v - mu;
  float q = d * d;
#pragma unroll
  for (int m = 32; m >= 1; m >>= 1) q += __shfl_xor(q, m);
  float var = q * 0.015625f;
  out[row * 64 + l] = d * rsqrtf(var + 1e-5f) * gamma[l] + beta[l];
}

extern "C" void kernel_launch(void* const* d_in, const int* in_sizes, int n_in,
                              void* d_out, int out_size, void* d_ws, size_t ws_size,
                              hipStream_t stream) {
  const float* x      = (const float*)d_in[0];
  const int*   eidx   = (const int*)d_in[1];
  const float* attr   = (const float*)d_in[2];
  const float* W_edge = (const float*)d_in[3];
  const float* b_edge = (const float*)d_in[4];
  const float* W_root = (const float*)d_in[5];
  const float* bias   = (const float*)d_in[6];
  const float* W_res  = (const float*)d_in[7];
  const float* b_res  = (const float*)d_in[8];
  const float* gamma  = (const float*)d_in[9];
  const float* beta   = (const float*)d_in[10];
  int N = in_sizes[0] / 64;
  int E = in_sizes[1] / 2;
  float* out = (float*)d_out;
  uint16_t* w2frag   = (uint16_t*)((char*)d_ws + W2FRAG_OFF);
  uint16_t* wsumfrag = (uint16_t*)((char*)d_ws + WSUM_OFF);
  float*    bsum     = (float*)((char*)d_ws + BSUM_OFF);

  prep_kernel<<<(PREP_TOTAL + 255) / 256, 256, 0, stream>>>(
      W_edge, b_edge, W_root, bias, W_res, b_res, w2frag, wsumfrag, bsum);
  base_kernel<<<(N + 63) / 64, 256, 0, stream>>>(x, wsumfrag, bsum, out, N);
  int T = (E + 63) / 64;
  int G = T < 512 ? T : 512;
  edge_kernel<<<G, 256, 0, stream>>>(x, eidx, attr, w2frag, out, E);
  ln_kernel<<<(N + 3) / 4, 256, 0, stream>>>(out, gamma, beta, N);
}